// Round 7
// baseline (416.559 us; speedup 1.0000x reference)
//
#include <hip/hip_runtime.h>
#include <math.h>

#define D 2048
#define E 64
#define NW 4                  // waves per block; each owns a 512-wide K-chunk
#define THREADS 256
#define TOK 32                // tokens per block
#define KCH (D / NW)          // 512
#define BK 8                  // k per staged W tile
#define NIT (KCH / BK)        // 64

// LDS map (bytes):
//  [0, 16384)     : per-wave W staging, wave w at w*4096 (two 2KB buffers)
//  [0, 16384)     : after K-loop barrier: tree tiles 0 (at 0) and 1 (at 8192)
//  [16384, 24704) : logits [32][65]
//  [24704, 25216) : sw1, sw2, si1, si2
#define SMEM_BYTES 25216

// ---- reduction-tile IO: tile = [32 tokens][64 experts] fp32 (8 KB) --------
// Address (row*64 + ec*4): bank quad = (ec*4)%32 -> ec and ec+8 alias 2-way,
// which is free (m136). acc[tt] covers tokens tr+4*tt.
__device__ __forceinline__ void tile_write(float* base, const float4 (&acc)[8],
                                           int tr, int ec) {
#pragma unroll
    for (int tt = 0; tt < 8; ++tt)
        *(float4*)(base + (tr + 4 * tt) * 64 + ec * 4) = acc[tt];
}

__device__ __forceinline__ void tile_add(const float* base, float4 (&acc)[8],
                                         int tr, int ec) {
#pragma unroll
    for (int tt = 0; tt < 8; ++tt) {
        float4 v = *(const float4*)(base + (tr + 4 * tt) * 64 + ec * 4);
        acc[tt].x += v.x; acc[tt].y += v.y;
        acc[tt].z += v.z; acc[tt].w += v.w;
    }
}

__global__ __launch_bounds__(THREADS, 2)
void gating_kernel(const float* __restrict__ x,
                   const float* __restrict__ W,
                   const float* __restrict__ Bv,
                   float* __restrict__ out)
{
    __shared__ __align__(16) char smem[SMEM_BYTES];

    const int tid  = threadIdx.x;
    const int lane = tid & 63;
    const int w    = tid >> 6;
    const int tok0 = blockIdx.x * TOK;
    const int tr = lane & 3;      // token row 0..3   (lane grid 4x16)
    const int ec = lane >> 2;     // expert col group 0..15 (4 experts each)

    // x row base pointers: rows tr, tr+4, ..., tr+28. 16 lanes share each
    // address -> 4 cache lines per load instruction (L1-friendly).
    const float* xb[8];
#pragma unroll
    for (int tt = 0; tt < 8; ++tt)
        xb[tt] = x + (size_t)(tok0 + tr + 4 * tt) * D + w * KCH;

    // W staging: tile it = rows [w*KCH + it*BK, +8) x 64 = 2KB contiguous.
    // Lane stages 2 float4s (linear layout, no swizzle).
    const float* wg = W + (size_t)w * KCH * E;   // tile it at +it*512 floats
    float* sbase = (float*)(smem + w * 4096);    // buf p at +p*512 floats

    float4 acc[8];
#pragma unroll
    for (int tt = 0; tt < 8; ++tt) acc[tt] = float4{0.f, 0.f, 0.f, 0.f};

    // ---- prologue: stage tile 0 into buf0, prefetch tile 1 ----
    float4 wr0 = *(const float4*)(wg + lane * 4);
    float4 wr1 = *(const float4*)(wg + 256 + lane * 4);
    *(float4*)(sbase + lane * 4) = wr0;
    *(float4*)(sbase + 256 + lane * 4) = wr1;
    wr0 = *(const float4*)(wg + 512 + lane * 4);
    wr1 = *(const float4*)(wg + 512 + 256 + lane * 4);

    // ---- K-loop: wave-private, no barriers. Stage tile it+1 into the other
    // buffer while computing tile it; prefetch tile it+2 from global.
    // DS ops are in-order within a wave; the it+1 writes target the buffer
    // whose reads completed during iteration it-1. ----
#pragma unroll 1
    for (int it = 0; it < NIT; ++it) {
        if (it + 1 < NIT) {
            float* nb = sbase + ((it + 1) & 1) * 512;
            *(float4*)(nb + lane * 4) = wr0;
            *(float4*)(nb + 256 + lane * 4) = wr1;
        }
        if (it + 2 < NIT) {
            wr0 = *(const float4*)(wg + (it + 2) * 512 + lane * 4);
            wr1 = *(const float4*)(wg + (it + 2) * 512 + 256 + lane * 4);
        }
        const float* ws = sbase + (it & 1) * 512;

#pragma unroll
        for (int u = 0; u < 2; ++u) {            // 2 units of 4 k
            float4 A[8];
#pragma unroll
            for (int tt = 0; tt < 8; ++tt)
                A[tt] = *(const float4*)(xb[tt] + it * BK + u * 4);
#pragma unroll
            for (int j = 0; j < 4; ++j) {
                float4 bf = *(const float4*)(ws + (u * 4 + j) * 64 + ec * 4);
#pragma unroll
                for (int tt = 0; tt < 8; ++tt) {
                    const float av = j == 0 ? A[tt].x : j == 1 ? A[tt].y
                                   : j == 2 ? A[tt].z : A[tt].w;
                    acc[tt].x = fmaf(av, bf.x, acc[tt].x);
                    acc[tt].y = fmaf(av, bf.y, acc[tt].y);
                    acc[tt].z = fmaf(av, bf.z, acc[tt].z);
                    acc[tt].w = fmaf(av, bf.w, acc[tt].w);
                }
            }
        }
    }

    // ---- cross-wave K-reduction: 2-level tree over 2 LDS tiles ----
    float* t0 = (float*)smem;
    float* t1 = (float*)(smem + 8192);
    __syncthreads();
    if (w >= 2) tile_write(w == 2 ? t0 : t1, acc, tr, ec);
    __syncthreads();
    if (w < 2)  tile_add(w == 0 ? t0 : t1, acc, tr, ec);  // w0+=w2, w1+=w3
    __syncthreads();
    if (w == 1) tile_write(t1, acc, tr, ec);
    __syncthreads();

    float* logits = (float*)(smem + 16384);      // [32][65]
    float* sw1 = (float*)(smem + 24704);
    float* sw2 = (float*)(smem + 24832);
    int*   si1 = (int*)  (smem + 24960);
    int*   si2 = (int*)  (smem + 25088);

    if (w == 0) {
        tile_add(t1, acc, tr, ec);               // full 4-way K sum
#pragma unroll
        for (int tt = 0; tt < 8; ++tt) {
            int row = tr + 4 * tt;
            logits[row * 65 + ec * 4 + 0] = acc[tt].x;
            logits[row * 65 + ec * 4 + 1] = acc[tt].y;
            logits[row * 65 + ec * 4 + 2] = acc[tt].z;
            logits[row * 65 + ec * 4 + 3] = acc[tt].w;
        }
    }
    __syncthreads();

    if (w == 0 && lane < TOK) {
        // lane = token: top-2 scan (+bias). Strict '>' matches top_k ties.
        // logits row stride 65 -> lane reads are conflict-free.
        float m1 = -3.4e38f, m2 = -3.4e38f;
        int i1 = 0, i2 = 0;
#pragma unroll
        for (int e = 0; e < E; ++e) {
            float v = logits[lane * 65 + e] + Bv[e];
            if (v > m1)      { m2 = m1; i2 = i1; m1 = v; i1 = e; }
            else if (v > m2) { m2 = v; i2 = e; }
        }
        float p = 1.0f / (1.0f + expf(m2 - m1)); // stable: m2 <= m1
        sw1[lane] = p; sw2[lane] = 1.0f - p;
        si1[lane] = i1; si2[lane] = i2;
    }
    __syncthreads();

    // ---- coalesced float4 store of the 32x64 tile (512 float4) ----
    float4* o4 = (float4*)(out + (size_t)tok0 * E);
#pragma unroll
    for (int r = 0; r < 2; ++r) {
        int idx = r * THREADS + tid;    // 0..511
        int tl  = idx >> 4;             // token 0..31
        int e0  = (idx & 15) * 4;
        int a1 = si1[tl], a2 = si2[tl];
        float v1 = sw1[tl], v2 = sw2[tl];
        float4 v;
        v.x = (e0 + 0 == a1) ? v1 : (e0 + 0 == a2) ? v2 : 0.0f;
        v.y = (e0 + 1 == a1) ? v1 : (e0 + 1 == a2) ? v2 : 0.0f;
        v.z = (e0 + 2 == a1) ? v1 : (e0 + 2 == a2) ? v2 : 0.0f;
        v.w = (e0 + 3 == a1) ? v1 : (e0 + 3 == a2) ? v2 : 0.0f;
        o4[idx] = v;
    }
}

extern "C" void kernel_launch(void* const* d_in, const int* in_sizes, int n_in,
                              void* d_out, int out_size, void* d_ws, size_t ws_size,
                              hipStream_t stream) {
    const float* x = (const float*)d_in[0];
    const float* W = (const float*)d_in[1];
    const float* b = (const float*)d_in[2];
    float* out = (float*)d_out;

    const int tokens = in_sizes[0] / D;      // 16384
    const int blocks = tokens / TOK;         // 512

    gating_kernel<<<blocks, THREADS, 0, stream>>>(x, W, b, out);
}